// Round 1
// baseline (557.583 us; speedup 1.0000x reference)
//
#include <hip/hip_runtime.h>

#define HW 65536
#define CB 64
#define NB 8
#define LDW 68   // padded LDS row stride (floats); 68%4==0 keeps float4 alignment

__device__ __forceinline__ float sigm(float v) { return 1.f / (1.f + __expf(-v)); }

// order-preserving float<->uint encode for atomicMax (memset-0 == -inf)
__device__ __forceinline__ unsigned encf(float f) {
    unsigned u = __float_as_uint(f);
    return (u & 0x80000000u) ? ~u : (u | 0x80000000u);
}
__device__ __forceinline__ float decf(unsigned u) {
    return (u & 0x80000000u) ? __uint_as_float(u & 0x7fffffffu) : __uint_as_float(~u);
}
__device__ __forceinline__ unsigned short f2bf(float f) {  // RNE
    unsigned u = __float_as_uint(f);
    u += 0x7fffu + ((u >> 16) & 1u);
    return (unsigned short)(u >> 16);
}
__device__ __forceinline__ float bf2f(unsigned short h) {
    return __uint_as_float(((unsigned)h) << 16);
}

// ---------------------------------------------------------------------------
// P1: one pass over x -> per-(b,c) sum/max (channel attention pooling) and
//     per-pixel channel mean/max (spatial attention input maps)
// grid = NB*64 (1024 px per block), block = 256
__global__ __launch_bounds__(256) void k_stats(
    const float* __restrict__ x, float* __restrict__ pool_sum,
    unsigned* __restrict__ pool_max, float* __restrict__ s_avg,
    float* __restrict__ s_max)
{
    const int t = threadIdx.x;
    const int b = blockIdx.x >> 6;
    const int pbase = (blockIdx.x & 63) << 10;
    const int lane = t & 63, wave = t >> 6;
    __shared__ float csum[4][CB];
    __shared__ float cmax[4][CB];

    float ps0 = 0, ps1 = 0, ps2 = 0, ps3 = 0;
    float pm0 = -1e30f, pm1 = -1e30f, pm2 = -1e30f, pm3 = -1e30f;
    const size_t base = (size_t)b * CB * HW + pbase + 4 * t;
    for (int c = 0; c < CB; ++c) {
        const float4 v = *(const float4*)(x + base + (size_t)c * HW);
        ps0 += v.x; ps1 += v.y; ps2 += v.z; ps3 += v.w;
        pm0 = fmaxf(pm0, v.x); pm1 = fmaxf(pm1, v.y);
        pm2 = fmaxf(pm2, v.z); pm3 = fmaxf(pm3, v.w);
        float cs = v.x + v.y + v.z + v.w;
        float cm = fmaxf(fmaxf(v.x, v.y), fmaxf(v.z, v.w));
        #pragma unroll
        for (int off = 32; off; off >>= 1) {
            cs += __shfl_xor(cs, off);
            cm = fmaxf(cm, __shfl_xor(cm, off));
        }
        if (lane == 0) { csum[wave][c] = cs; cmax[wave][c] = cm; }
    }
    __syncthreads();
    if (t < CB) {
        const float s = csum[0][t] + csum[1][t] + csum[2][t] + csum[3][t];
        const float m = fmaxf(fmaxf(cmax[0][t], cmax[1][t]), fmaxf(cmax[2][t], cmax[3][t]));
        atomicAdd(&pool_sum[b * CB + t], s);
        atomicMax(&pool_max[b * CB + t], encf(m));
    }
    const float inv = 1.f / 64.f;
    float4 sa4 = {ps0 * inv, ps1 * inv, ps2 * inv, ps3 * inv};
    float4 sm4 = {pm0, pm1, pm2, pm3};
    *(float4*)(s_avg + (size_t)b * HW + pbase + 4 * t) = sa4;
    *(float4*)(s_max + (size_t)b * HW + pbase + 4 * t) = sm4;
}

// ---------------------------------------------------------------------------
// P2: channel-attention MLP. grid = NB, block = 64
__global__ __launch_bounds__(64) void k_ca(
    const float* __restrict__ pool_sum, const unsigned* __restrict__ pool_max,
    const float* __restrict__ w1, const float* __restrict__ w2,
    float* __restrict__ ca)
{
    __shared__ float av[CB], mv[CB], hh[8];
    const int b = blockIdx.x, t = threadIdx.x;
    av[t] = pool_sum[b * CB + t] * (1.f / (float)HW);
    mv[t] = decf(pool_max[b * CB + t]);
    __syncthreads();
    if (t < 8) {
        const int h = t & 3;
        const float* v = (t < 4) ? av : mv;
        float s = 0;
        for (int c = 0; c < CB; ++c) s += w1[h * CB + c] * v[c];
        hh[t] = fmaxf(s, 0.f);   // relu(W1 . v)
    }
    __syncthreads();
    float s = 0;
    #pragma unroll
    for (int h = 0; h < 4; ++h) s += w2[t * 4 + h] * (hh[h] + hh[4 + h]);
    ca[b * CB + t] = sigm(s);
}

// ---------------------------------------------------------------------------
// P3: 7x7 spatial-attention conv over [mean,max] maps -> sigmoid.
// grid = NB*256, block = 256 (one row per block -> uniform row-bound branches)
__global__ __launch_bounds__(256) void k_saconv(
    const float* __restrict__ s_avg, const float* __restrict__ s_max,
    const float* __restrict__ w, float* __restrict__ sa)
{
    const int b = blockIdx.x >> 8;
    const int pix = ((blockIdx.x & 255) << 8) | threadIdx.x;
    const int i = pix >> 8, j = pix & 255;
    float acc = 0.f;
    #pragma unroll
    for (int cin = 0; cin < 2; ++cin) {
        const float* src = (cin ? s_max : s_avg) + (size_t)b * HW;
        const float* wk = w + cin * 49;
        #pragma unroll
        for (int ki = 0; ki < 7; ++ki) {
            const int y = i + ki - 3;
            if ((unsigned)y < 256u) {
                #pragma unroll
                for (int kj = 0; kj < 7; ++kj) {
                    const int xx = j + kj - 3;
                    if ((unsigned)xx < 256u) acc += src[(y << 8) | xx] * wk[ki * 7 + kj];
                }
            }
        }
    }
    sa[(size_t)b * HW + pix] = sigm(acc);
}

#define FMA16(WV, FV)                                                                   \
    acc[0][0] += WV.x * FV.x; acc[0][1] += WV.x * FV.y; acc[0][2] += WV.x * FV.z; acc[0][3] += WV.x * FV.w; \
    acc[1][0] += WV.y * FV.x; acc[1][1] += WV.y * FV.y; acc[1][2] += WV.y * FV.z; acc[1][3] += WV.y * FV.w; \
    acc[2][0] += WV.z * FV.x; acc[2][1] += WV.z * FV.y; acc[2][2] += WV.z * FV.z; acc[2][3] += WV.z * FV.w; \
    acc[3][0] += WV.w * FV.x; acc[3][1] += WV.w * FV.y; acc[3][2] += WV.w * FV.z; acc[3][3] += WV.w * FV.w;

// ---------------------------------------------------------------------------
// P4: the heavy kernel. Per 64-pixel tile: fuse = x*(sa+ca); guide = sigmoid(G@fuse);
// xg = x*guide*mask(last row/col); d = Wd@xg + b. Writes d (bf16) + GN stats.
// grid = NB*1024, block = 256. LDS ~53KB -> 3 blocks/CU.
__global__ __launch_bounds__(256) void k_main(
    const float* __restrict__ x, const float* __restrict__ sa,
    const float* __restrict__ ca, const float* __restrict__ gw,
    const float* __restrict__ dw, const float* __restrict__ db,
    unsigned short* __restrict__ dbuf, float* __restrict__ gn_sum,
    float* __restrict__ gn_sq)
{
    __shared__ float xt[CB][LDW];   // x tile; later reused as WT (dsc_w^T)
    __shared__ float ft[CB][LDW];   // fuse tile; later xg tile
    __shared__ float GT[CB][LDW];   // gate_w^T: GT[k][c] = gw[c*64+k]
    __shared__ float cav[CB];
    __shared__ float scav[CB];

    const int t = threadIdx.x;
    const int b = blockIdx.x >> 10;
    const int pbase = (blockIdx.x & 1023) << 6;

    float wreg[16];
    #pragma unroll
    for (int it = 0; it < 16; ++it) {
        const int idx = (it << 8) + t;
        wreg[it] = dw[idx];                 // stash dsc_w in regs for later
        GT[idx & 63][idx >> 6] = gw[idx];   // transpose store (one-time)
    }
    if (t < CB) {
        cav[t] = ca[b * CB + t];
        scav[t] = sa[(size_t)b * HW + pbase + t];
    }
    __syncthreads();

    {   // load x tile, compute fuse
        const int pl = t & 63;
        const int cb0 = t >> 6;
        const float sval = scav[pl];
        #pragma unroll
        for (int i = 0; i < 16; ++i) {
            const int c = cb0 + (i << 2);
            const float v = x[((size_t)(b * CB + c)) * HW + pbase + pl];
            xt[c][pl] = v;
            ft[c][pl] = v * (sval + cav[c]);
        }
    }
    __syncthreads();

    const int c0 = (t >> 4) << 2;
    const int p0 = (t & 15) << 2;

    float acc[4][4];
    #pragma unroll
    for (int i = 0; i < 4; ++i) { acc[i][0] = 0; acc[i][1] = 0; acc[i][2] = 0; acc[i][3] = 0; }
    #pragma unroll 4
    for (int k = 0; k < CB; ++k) {   // GEMM1: guide logits
        const float4 fv = *(const float4*)&ft[k][p0];
        const float4 wv = *(const float4*)&GT[k][c0];
        FMA16(wv, fv)
    }
    __syncthreads();   // all GEMM1 reads of ft/xt-safe point

    // xg = x * sigmoid(logit) * mask; mask zeroes last row (i==255) / col (j==255)
    const int prow255 = ((pbase >> 8) == 255);
    const int pcb = (pbase + p0) & 255;
    #pragma unroll
    for (int i = 0; i < 4; ++i) {
        const float4 xv = *(const float4*)&xt[c0 + i][p0];
        float4 xg;
        xg.x = (prow255 || pcb + 0 == 255) ? 0.f : xv.x * sigm(acc[i][0]);
        xg.y = (prow255 || pcb + 1 == 255) ? 0.f : xv.y * sigm(acc[i][1]);
        xg.z = (prow255 || pcb + 2 == 255) ? 0.f : xv.z * sigm(acc[i][2]);
        xg.w = (prow255 || pcb + 3 == 255) ? 0.f : xv.w * sigm(acc[i][3]);
        *(float4*)&ft[c0 + i][p0] = xg;
    }
    __syncthreads();   // xg written, xt reads done

    #pragma unroll
    for (int it = 0; it < 16; ++it) {   // WT into xt space
        const int idx = (it << 8) + t;
        xt[idx & 63][idx >> 6] = wreg[it];
    }
    __syncthreads();

    #pragma unroll
    for (int i = 0; i < 4; ++i) { acc[i][0] = 0; acc[i][1] = 0; acc[i][2] = 0; acc[i][3] = 0; }
    #pragma unroll 4
    for (int k = 0; k < CB; ++k) {   // GEMM2: d = Wd @ xg
        const float4 fv = *(const float4*)&ft[k][p0];
        const float4 wv = *(const float4*)&xt[k][c0];
        FMA16(wv, fv)
    }

    float gs = 0.f, gq = 0.f;
    #pragma unroll
    for (int i = 0; i < 4; ++i) {
        const float bias = db[c0 + i];
        const float d0 = acc[i][0] + bias, d1 = acc[i][1] + bias;
        const float d2 = acc[i][2] + bias, d3 = acc[i][3] + bias;
        ushort4 o; o.x = f2bf(d0); o.y = f2bf(d1); o.z = f2bf(d2); o.w = f2bf(d3);
        *(ushort4*)&dbuf[((size_t)(b * CB + c0 + i)) * HW + pbase + p0] = o;
        gs += d0 + d1 + d2 + d3;
        gq += d0 * d0 + d1 * d1 + d2 * d2 + d3 * d3;
    }
    // c0..c0+3 is exactly one GN group (g = t>>4); reduce across the 16 lanes sharing it
    #pragma unroll
    for (int off = 8; off; off >>= 1) { gs += __shfl_xor(gs, off); gq += __shfl_xor(gq, off); }
    if ((t & 15) == 0) {
        atomicAdd(&gn_sum[b * 16 + (t >> 4)], gs);
        atomicAdd(&gn_sq[b * 16 + (t >> 4)], gq);
    }
}

// ---------------------------------------------------------------------------
// GN finalize -> per-(b,c) affine. 1 block, 512 threads.
__global__ void k_fin_gn(const float* __restrict__ gn_sum, const float* __restrict__ gn_sq,
                         const float* __restrict__ gamma, const float* __restrict__ beta,
                         float* __restrict__ gn_a, float* __restrict__ gn_b)
{
    const int t = threadIdx.x;          // t = b*64 + c
    const int b = t >> 6, c = t & 63, g = c >> 2;
    const float n = 4.f * (float)HW;
    const float mu = gn_sum[b * 16 + g] / n;
    const float var = gn_sq[b * 16 + g] / n - mu * mu;
    const float a = rsqrtf(var + 1e-5f) * gamma[c];
    gn_a[t] = a;
    gn_b[t] = beta[c] - mu * a;
}

// ---------------------------------------------------------------------------
// P5: y = relu(GN(d)) + x, in-place (d->y in dbuf), accumulate BN stats.
// grid = NB*CB*64, block = 256 (1024 px per block)
__global__ __launch_bounds__(256) void k_gnbn(
    const float* __restrict__ x, unsigned short* __restrict__ dy,
    const float* __restrict__ gn_a, const float* __restrict__ gn_b,
    float* __restrict__ bn_sum, float* __restrict__ bn_sq)
{
    const int t = threadIdx.x;
    const int bc = blockIdx.x >> 6;
    const int c = bc & 63;
    const size_t base = (size_t)bc * HW + ((size_t)(blockIdx.x & 63) << 10) + (t << 2);
    const float a = gn_a[bc], bb = gn_b[bc];
    const ushort4 d4 = *(const ushort4*)(dy + base);
    const float4 xv = *(const float4*)(x + base);
    const float y0 = fmaxf(bf2f(d4.x) * a + bb, 0.f) + xv.x;
    const float y1 = fmaxf(bf2f(d4.y) * a + bb, 0.f) + xv.y;
    const float y2 = fmaxf(bf2f(d4.z) * a + bb, 0.f) + xv.z;
    const float y3 = fmaxf(bf2f(d4.w) * a + bb, 0.f) + xv.w;
    ushort4 o; o.x = f2bf(y0); o.y = f2bf(y1); o.z = f2bf(y2); o.w = f2bf(y3);
    *(ushort4*)(dy + base) = o;
    float bs = y0 + y1 + y2 + y3;
    float bq = y0 * y0 + y1 * y1 + y2 * y2 + y3 * y3;
    #pragma unroll
    for (int off = 32; off; off >>= 1) { bs += __shfl_xor(bs, off); bq += __shfl_xor(bq, off); }
    __shared__ float rs[4], rq[4];
    if ((t & 63) == 0) { rs[t >> 6] = bs; rq[t >> 6] = bq; }
    __syncthreads();
    if (t == 0) {
        atomicAdd(&bn_sum[c], rs[0] + rs[1] + rs[2] + rs[3]);
        atomicAdd(&bn_sq[c], rq[0] + rq[1] + rq[2] + rq[3]);
    }
}

// BN finalize. 1 block, 64 threads.
__global__ void k_fin_bn(const float* __restrict__ bn_sum, const float* __restrict__ bn_sq,
                         const float* __restrict__ gamma, const float* __restrict__ beta,
                         float* __restrict__ bn_a, float* __restrict__ bn_b)
{
    const int c = threadIdx.x;
    const float n = (float)(NB * (size_t)HW);
    const float mu = bn_sum[c] / n;
    const float var = bn_sq[c] / n - mu * mu;
    const float a = rsqrtf(var + 1e-5f) * gamma[c];
    bn_a[c] = a;
    bn_b[c] = beta[c] - mu * a;
}

// ---------------------------------------------------------------------------
// P6: out = out_b + sum_c out_w[c] * prelu(BN(y)). grid = NB*64, block = 256
__global__ __launch_bounds__(256) void k_out(
    const unsigned short* __restrict__ y, const float* __restrict__ bn_a,
    const float* __restrict__ bn_b, const float* __restrict__ pa,
    const float* __restrict__ ow, const float* __restrict__ ob,
    float* __restrict__ out)
{
    const int t = threadIdx.x;
    const int b = blockIdx.x >> 6;
    const int p = ((blockIdx.x & 63) << 10) + (t << 2);
    const float alpha = pa[0];
    const float obv = ob[0];
    float a0 = obv, a1 = obv, a2 = obv, a3 = obv;
    for (int c = 0; c < CB; ++c) {
        const ushort4 v = *(const ushort4*)(y + ((size_t)(b * CB + c)) * HW + p);
        const float s = bn_a[c], sh = bn_b[c], w = ow[c];
        float t0 = bf2f(v.x) * s + sh; t0 = t0 >= 0.f ? t0 : alpha * t0; a0 += w * t0;
        float t1 = bf2f(v.y) * s + sh; t1 = t1 >= 0.f ? t1 : alpha * t1; a1 += w * t1;
        float t2 = bf2f(v.z) * s + sh; t2 = t2 >= 0.f ? t2 : alpha * t2; a2 += w * t2;
        float t3 = bf2f(v.w) * s + sh; t3 = t3 >= 0.f ? t3 : alpha * t3; a3 += w * t3;
    }
    float4 o = {a0, a1, a2, a3};
    *(float4*)(out + (size_t)b * HW + p) = o;
}

// ---------------------------------------------------------------------------
extern "C" void kernel_launch(void* const* d_in, const int* in_sizes, int n_in,
                              void* d_out, int out_size, void* d_ws, size_t ws_size,
                              hipStream_t stream)
{
    const float* x        = (const float*)d_in[0];
    const float* ca_w1    = (const float*)d_in[1];
    const float* ca_w2    = (const float*)d_in[2];
    const float* sa_w     = (const float*)d_in[3];
    const float* gate_w   = (const float*)d_in[4];
    // d_in[5..8]: offset branch — dead in forward math, skipped
    const float* dsc_w    = (const float*)d_in[9];
    const float* dsc_b    = (const float*)d_in[10];
    const float* gn_gamma = (const float*)d_in[11];
    const float* gn_beta  = (const float*)d_in[12];
    const float* bn_gamma = (const float*)d_in[13];
    const float* bn_beta  = (const float*)d_in[14];
    const float* prelu_a  = (const float*)d_in[15];
    const float* out_w    = (const float*)d_in[16];
    const float* out_b    = (const float*)d_in[17];
    float* out = (float*)d_out;

    char* ws = (char*)d_ws;
    size_t off = 0;
    auto alloc = [&](size_t bytes) -> char* {
        char* p = ws + off;
        off = (off + bytes + 255) & ~(size_t)255;
        return p;
    };
    unsigned short* dbuf = (unsigned short*)alloc((size_t)NB * CB * HW * 2);  // d, then y (bf16)
    float* s_avg = (float*)alloc((size_t)NB * HW * 4);
    float* s_max = (float*)alloc((size_t)NB * HW * 4);
    float* sa    = (float*)alloc((size_t)NB * HW * 4);
    float* cav   = (float*)alloc(512 * 4);
    float* gn_a  = (float*)alloc(512 * 4);
    float* gn_b  = (float*)alloc(512 * 4);
    float* bn_a  = (float*)alloc(64 * 4);
    float* bn_b  = (float*)alloc(64 * 4);
    char* stats  = alloc(1408 * 4);   // contiguous zeroed accumulators
    float*    pool_sum = (float*)stats;
    unsigned* pool_max = (unsigned*)(stats + 512 * 4);
    float*    gn_sum   = (float*)(stats + 1024 * 4);
    float*    gn_sq    = (float*)(stats + 1152 * 4);
    float*    bn_sum   = (float*)(stats + 1280 * 4);
    float*    bn_sq    = (float*)(stats + 1344 * 4);
    (void)in_sizes; (void)n_in; (void)out_size; (void)ws_size;

    hipMemsetAsync(stats, 0, 1408 * 4, stream);

    k_stats <<<NB * 64,      256, 0, stream>>>(x, pool_sum, pool_max, s_avg, s_max);
    k_ca    <<<NB,            64, 0, stream>>>(pool_sum, pool_max, ca_w1, ca_w2, cav);
    k_saconv<<<NB * 256,     256, 0, stream>>>(s_avg, s_max, sa_w, sa);
    k_main  <<<NB * 1024,    256, 0, stream>>>(x, sa, cav, gate_w, dsc_w, dsc_b, dbuf, gn_sum, gn_sq);
    k_fin_gn<<<1,            512, 0, stream>>>(gn_sum, gn_sq, gn_gamma, gn_beta, gn_a, gn_b);
    k_gnbn  <<<NB * CB * 64, 256, 0, stream>>>(x, dbuf, gn_a, gn_b, bn_sum, bn_sq);
    k_fin_bn<<<1,             64, 0, stream>>>(bn_sum, bn_sq, bn_gamma, bn_beta, bn_a, bn_b);
    k_out   <<<NB * 64,      256, 0, stream>>>(dbuf, bn_a, bn_b, prelu_a, out_w, out_b, out);
}

// Round 2
// 193.094 us; speedup vs baseline: 2.8876x; 2.8876x over previous
//
#include <hip/hip_runtime.h>

#define HW 65536
#define CB 64
#define NB 8

typedef __attribute__((ext_vector_type(4))) float f32x4;
typedef __attribute__((ext_vector_type(8))) short s16x8;

__device__ __forceinline__ float sigm(float v) { return 1.f / (1.f + __expf(-v)); }

__device__ __forceinline__ unsigned encf(float f) {
    unsigned u = __float_as_uint(f);
    return (u & 0x80000000u) ? ~u : (u | 0x80000000u);
}
__device__ __forceinline__ float decf(unsigned u) {
    return (u & 0x80000000u) ? __uint_as_float(u & 0x7fffffffu) : __uint_as_float(~u);
}
__device__ __forceinline__ unsigned f2bf(float f) {  // RNE, returns low 16 bits
    unsigned u = __float_as_uint(f);
    u += 0x7fffu + ((u >> 16) & 1u);
    return u >> 16;
}
__device__ __forceinline__ float bf2f(unsigned h) {
    return __uint_as_float(h << 16);
}
// swizzled word index for [row][32-word] bf16 tiles (row stride 128B)
__device__ __forceinline__ int swz(int row, int w) { return (row << 5) + (w ^ ((row & 7) << 2)); }

// ---------------------------------------------------------------------------
// P1: per-(b,c) sum/max pooling + per-pixel channel mean/max
__global__ __launch_bounds__(256) void k_stats(
    const float* __restrict__ x, float* __restrict__ pool_sum,
    unsigned* __restrict__ pool_max, float* __restrict__ s_avg,
    float* __restrict__ s_max)
{
    const int t = threadIdx.x;
    const int b = blockIdx.x >> 6;
    const int pbase = (blockIdx.x & 63) << 10;
    const int lane = t & 63, wave = t >> 6;
    __shared__ float csum[4][CB];
    __shared__ float cmax[4][CB];

    float ps0 = 0, ps1 = 0, ps2 = 0, ps3 = 0;
    float pm0 = -1e30f, pm1 = -1e30f, pm2 = -1e30f, pm3 = -1e30f;
    const size_t base = (size_t)b * CB * HW + pbase + 4 * t;
    for (int c = 0; c < CB; ++c) {
        const float4 v = *(const float4*)(x + base + (size_t)c * HW);
        ps0 += v.x; ps1 += v.y; ps2 += v.z; ps3 += v.w;
        pm0 = fmaxf(pm0, v.x); pm1 = fmaxf(pm1, v.y);
        pm2 = fmaxf(pm2, v.z); pm3 = fmaxf(pm3, v.w);
        float cs = v.x + v.y + v.z + v.w;
        float cm = fmaxf(fmaxf(v.x, v.y), fmaxf(v.z, v.w));
        #pragma unroll
        for (int off = 32; off; off >>= 1) {
            cs += __shfl_xor(cs, off);
            cm = fmaxf(cm, __shfl_xor(cm, off));
        }
        if (lane == 0) { csum[wave][c] = cs; cmax[wave][c] = cm; }
    }
    __syncthreads();
    if (t < CB) {
        const float s = csum[0][t] + csum[1][t] + csum[2][t] + csum[3][t];
        const float m = fmaxf(fmaxf(cmax[0][t], cmax[1][t]), fmaxf(cmax[2][t], cmax[3][t]));
        atomicAdd(&pool_sum[b * CB + t], s);
        atomicMax(&pool_max[b * CB + t], encf(m));
    }
    const float inv = 1.f / 64.f;
    float4 sa4 = {ps0 * inv, ps1 * inv, ps2 * inv, ps3 * inv};
    float4 sm4 = {pm0, pm1, pm2, pm3};
    *(float4*)(s_avg + (size_t)b * HW + pbase + 4 * t) = sa4;
    *(float4*)(s_max + (size_t)b * HW + pbase + 4 * t) = sm4;
}

// ---------------------------------------------------------------------------
__global__ __launch_bounds__(64) void k_ca(
    const float* __restrict__ pool_sum, const unsigned* __restrict__ pool_max,
    const float* __restrict__ w1, const float* __restrict__ w2,
    float* __restrict__ ca)
{
    __shared__ float av[CB], mv[CB], hh[8];
    const int b = blockIdx.x, t = threadIdx.x;
    av[t] = pool_sum[b * CB + t] * (1.f / (float)HW);
    mv[t] = decf(pool_max[b * CB + t]);
    __syncthreads();
    if (t < 8) {
        const int h = t & 3;
        const float* v = (t < 4) ? av : mv;
        float s = 0;
        for (int c = 0; c < CB; ++c) s += w1[h * CB + c] * v[c];
        hh[t] = fmaxf(s, 0.f);
    }
    __syncthreads();
    float s = 0;
    #pragma unroll
    for (int h = 0; h < 4; ++h) s += w2[t * 4 + h] * (hh[h] + hh[4 + h]);
    ca[b * CB + t] = sigm(s);
}

// ---------------------------------------------------------------------------
__global__ __launch_bounds__(256) void k_saconv(
    const float* __restrict__ s_avg, const float* __restrict__ s_max,
    const float* __restrict__ w, float* __restrict__ sa)
{
    const int b = blockIdx.x >> 8;
    const int pix = ((blockIdx.x & 255) << 8) | threadIdx.x;
    const int i = pix >> 8, j = pix & 255;
    float acc = 0.f;
    #pragma unroll
    for (int cin = 0; cin < 2; ++cin) {
        const float* src = (cin ? s_max : s_avg) + (size_t)b * HW;
        const float* wk = w + cin * 49;
        #pragma unroll
        for (int ki = 0; ki < 7; ++ki) {
            const int y = i + ki - 3;
            if ((unsigned)y < 256u) {
                #pragma unroll
                for (int kj = 0; kj < 7; ++kj) {
                    const int xx = j + kj - 3;
                    if ((unsigned)xx < 256u) acc += src[(y << 8) | xx] * wk[ki * 7 + kj];
                }
            }
        }
    }
    sa[(size_t)b * HW + pix] = sigm(acc);
}

// ---------------------------------------------------------------------------
// P4: MFMA version. 128-px tile per block, 4 waves. Per wave: ch-block m=wv,
// 8 px n-tiles. LDS: WG[0..2047] WD[2048..4095] FT[4096..8191] XT[8192..12287]
// (uint words), sums @12288. All bf16 tiles [row][64ch] with XOR swizzle.
__global__ __launch_bounds__(256, 3) void k_main(
    const float* __restrict__ x, const float* __restrict__ sa,
    const float* __restrict__ ca, const float* __restrict__ gw,
    const float* __restrict__ dw, const float* __restrict__ db,
    unsigned short* __restrict__ dbuf, float* __restrict__ gn_sum,
    float* __restrict__ gn_sq)
{
    __shared__ unsigned lds[12320];
    const int t = threadIdx.x;
    const int wv = t >> 6, l = t & 63, hi = l >> 4, lo = l & 15;
    const int b = blockIdx.x >> 9;
    const int pbase = (blockIdx.x & 511) << 7;

    // ---- stage weights: [outch][k] bf16, swizzled ----
    {
        const int orow = t >> 2, cq = (t & 3) << 4;
        const float* gsrc = gw + (orow << 6) + cq;
        const float* dsrc = dw + (orow << 6) + cq;
        unsigned ug[8], ud[8];
        #pragma unroll
        for (int j = 0; j < 8; ++j) {
            ug[j] = f2bf(gsrc[2 * j]) | (f2bf(gsrc[2 * j + 1]) << 16);
            ud[j] = f2bf(dsrc[2 * j]) | (f2bf(dsrc[2 * j + 1]) << 16);
        }
        const int wbase = (t & 3) << 3;
        *(uint4*)&lds[swz(orow, wbase)]            = make_uint4(ug[0], ug[1], ug[2], ug[3]);
        *(uint4*)&lds[swz(orow, wbase + 4)]        = make_uint4(ug[4], ug[5], ug[6], ug[7]);
        *(uint4*)&lds[2048 + swz(orow, wbase)]     = make_uint4(ud[0], ud[1], ud[2], ud[3]);
        *(uint4*)&lds[2048 + swz(orow, wbase + 4)] = make_uint4(ud[4], ud[5], ud[6], ud[7]);
    }

    // ---- stage x (XT) and fuse (FT): [px][ch] bf16, swizzled ----
    {
        const int px0 = l << 1;
        const float2 sv = *(const float2*)(sa + (size_t)b * HW + pbase + px0);
        unsigned ux0[8], ux1[8], uf0[8], uf1[8];
        #pragma unroll
        for (int j2 = 0; j2 < 8; ++j2) {
            const int c0 = (wv << 4) + 2 * j2;
            const float cv0 = ca[(b << 6) + c0];
            const float cv1 = ca[(b << 6) + c0 + 1];
            const float2 v0 = *(const float2*)(x + ((size_t)((b << 6) + c0)) * HW + pbase + px0);
            const float2 v1 = *(const float2*)(x + ((size_t)((b << 6) + c0 + 1)) * HW + pbase + px0);
            ux0[j2] = f2bf(v0.x) | (f2bf(v1.x) << 16);
            ux1[j2] = f2bf(v0.y) | (f2bf(v1.y) << 16);
            uf0[j2] = f2bf(v0.x * (sv.x + cv0)) | (f2bf(v1.x * (sv.x + cv1)) << 16);
            uf1[j2] = f2bf(v0.y * (sv.y + cv0)) | (f2bf(v1.y * (sv.y + cv1)) << 16);
        }
        const int wb = wv << 3;
        *(uint4*)&lds[8192 + swz(px0, wb)]         = make_uint4(ux0[0], ux0[1], ux0[2], ux0[3]);
        *(uint4*)&lds[8192 + swz(px0, wb + 4)]     = make_uint4(ux0[4], ux0[5], ux0[6], ux0[7]);
        *(uint4*)&lds[8192 + swz(px0 + 1, wb)]     = make_uint4(ux1[0], ux1[1], ux1[2], ux1[3]);
        *(uint4*)&lds[8192 + swz(px0 + 1, wb + 4)] = make_uint4(ux1[4], ux1[5], ux1[6], ux1[7]);
        *(uint4*)&lds[4096 + swz(px0, wb)]         = make_uint4(uf0[0], uf0[1], uf0[2], uf0[3]);
        *(uint4*)&lds[4096 + swz(px0, wb + 4)]     = make_uint4(uf0[4], uf0[5], uf0[6], uf0[7]);
        *(uint4*)&lds[4096 + swz(px0 + 1, wb)]     = make_uint4(uf1[0], uf1[1], uf1[2], uf1[3]);
        *(uint4*)&lds[4096 + swz(px0 + 1, wb + 4)] = make_uint4(uf1[4], uf1[5], uf1[6], uf1[7]);
    }
    __syncthreads();

    // ---- GEMM1: guide logits = gate_w @ fuse ----
    f32x4 acc[8];
    #pragma unroll
    for (int n = 0; n < 8; ++n) acc[n] = (f32x4){0.f, 0.f, 0.f, 0.f};
    {
        const int arow = (wv << 4) + lo;
        const s16x8 a0 = __builtin_bit_cast(s16x8, *(const uint4*)&lds[swz(arow, hi << 2)]);
        const s16x8 a1 = __builtin_bit_cast(s16x8, *(const uint4*)&lds[swz(arow, (hi << 2) + 16)]);
        #pragma unroll
        for (int n = 0; n < 8; ++n) {
            const int brow = (n << 4) + lo;
            const s16x8 b0 = __builtin_bit_cast(s16x8, *(const uint4*)&lds[4096 + swz(brow, hi << 2)]);
            const s16x8 b1 = __builtin_bit_cast(s16x8, *(const uint4*)&lds[4096 + swz(brow, (hi << 2) + 16)]);
            acc[n] = __builtin_amdgcn_mfma_f32_16x16x32_bf16(a0, b0, acc[n], 0, 0, 0);
            acc[n] = __builtin_amdgcn_mfma_f32_16x16x32_bf16(a1, b1, acc[n], 0, 0, 0);
        }
    }
    __syncthreads();

    // ---- xg = x * sigmoid(logit) * mask, into FT ----
    {
        const bool row255 = (pbase >> 8) == 255;
        const bool halfblk = (pbase & 128) != 0;
        const int wb2 = (wv << 3) + (hi << 1);
        #pragma unroll
        for (int n = 0; n < 8; ++n) {
            const int pxl = (n << 4) + lo;
            const uint2 xv = *(const uint2*)&lds[8192 + swz(pxl, wb2)];
            const bool zero = row255 || (halfblk && pxl == 127);
            float xg0 = zero ? 0.f : bf2f(xv.x & 0xffffu) * sigm(acc[n][0]);
            float xg1 = zero ? 0.f : bf2f(xv.x >> 16)     * sigm(acc[n][1]);
            float xg2 = zero ? 0.f : bf2f(xv.y & 0xffffu) * sigm(acc[n][2]);
            float xg3 = zero ? 0.f : bf2f(xv.y >> 16)     * sigm(acc[n][3]);
            uint2 o;
            o.x = f2bf(xg0) | (f2bf(xg1) << 16);
            o.y = f2bf(xg2) | (f2bf(xg3) << 16);
            *(uint2*)&lds[4096 + swz(pxl, wb2)] = o;
        }
    }
    __syncthreads();

    // ---- GEMM2: d = dsc_w @ xg ----
    f32x4 acc2[8];
    #pragma unroll
    for (int n = 0; n < 8; ++n) acc2[n] = (f32x4){0.f, 0.f, 0.f, 0.f};
    {
        const int arow = (wv << 4) + lo;
        const s16x8 a0 = __builtin_bit_cast(s16x8, *(const uint4*)&lds[2048 + swz(arow, hi << 2)]);
        const s16x8 a1 = __builtin_bit_cast(s16x8, *(const uint4*)&lds[2048 + swz(arow, (hi << 2) + 16)]);
        #pragma unroll
        for (int n = 0; n < 8; ++n) {
            const int brow = (n << 4) + lo;
            const s16x8 b0 = __builtin_bit_cast(s16x8, *(const uint4*)&lds[4096 + swz(brow, hi << 2)]);
            const s16x8 b1 = __builtin_bit_cast(s16x8, *(const uint4*)&lds[4096 + swz(brow, (hi << 2) + 16)]);
            acc2[n] = __builtin_amdgcn_mfma_f32_16x16x32_bf16(a0, b0, acc2[n], 0, 0, 0);
            acc2[n] = __builtin_amdgcn_mfma_f32_16x16x32_bf16(a1, b1, acc2[n], 0, 0, 0);
        }
    }

    // ---- epilogue: bias, GN partial stats, d -> XT region ([ch][64w]) ----
    float gs = 0.f, gq = 0.f;
    {
        const float4 bv = *(const float4*)(db + (wv << 4) + (hi << 2));
        const float bvr[4] = {bv.x, bv.y, bv.z, bv.w};
        unsigned short* lds16 = (unsigned short*)lds;
        #pragma unroll
        for (int n = 0; n < 8; ++n) {
            const int pxl = (n << 4) + lo;
            #pragma unroll
            for (int r = 0; r < 4; ++r) {
                const float dvf = acc2[n][r] + bvr[r];
                gs += dvf; gq += dvf * dvf;
                const int ch = (wv << 4) + (hi << 2) + r;
                const int w64 = (pxl >> 1) ^ ((ch & 7) << 2);
                lds16[((8192 + (ch << 6) + w64) << 1) + (pxl & 1)] = (unsigned short)f2bf(dvf);
            }
        }
    }
    #pragma unroll
    for (int o = 1; o < 16; o <<= 1) { gs += __shfl_xor(gs, o); gq += __shfl_xor(gq, o); }
    float* smf = (float*)&lds[12288];
    if (lo == 0) { smf[(((wv << 2) + hi) << 1)] = gs; smf[(((wv << 2) + hi) << 1) + 1] = gq; }
    __syncthreads();
    if (t < 16) {
        atomicAdd(&gn_sum[(b << 4) + t], smf[2 * t]);
        atomicAdd(&gn_sq[(b << 4) + t],  smf[2 * t + 1]);
    }
    // coalesced bf16 store of d
    {
        const int ch = t >> 2, sub = t & 3;
        unsigned short* dst = dbuf + ((size_t)((b << 6) + ch)) * HW + pbase;
        #pragma unroll
        for (int j = 0; j < 4; ++j) {
            const int w64 = ((j << 4) + (sub << 2)) ^ ((ch & 7) << 2);
            const uint4 dv = *(const uint4*)&lds[8192 + (ch << 6) + w64];
            *(uint4*)(dst + (j << 5) + (sub << 3)) = dv;
        }
    }
}

// ---------------------------------------------------------------------------
__global__ void k_fin_gn(const float* __restrict__ gn_sum, const float* __restrict__ gn_sq,
                         const float* __restrict__ gamma, const float* __restrict__ beta,
                         float* __restrict__ gn_a, float* __restrict__ gn_b)
{
    const int t = threadIdx.x;
    const int b = t >> 6, c = t & 63, g = c >> 2;
    const float n = 4.f * (float)HW;
    const float mu = gn_sum[b * 16 + g] / n;
    const float var = gn_sq[b * 16 + g] / n - mu * mu;
    const float a = rsqrtf(var + 1e-5f) * gamma[c];
    gn_a[t] = a;
    gn_b[t] = beta[c] - mu * a;
}

// ---------------------------------------------------------------------------
// P5: y = relu(GN(d)) + x in-place, BN partial stats. grid = NB*CB*4.
__global__ __launch_bounds__(256) void k_gnbn(
    const float* __restrict__ x, unsigned short* __restrict__ dy,
    const float* __restrict__ gn_a, const float* __restrict__ gn_b,
    float* __restrict__ bn_sum, float* __restrict__ bn_sq)
{
    const int t = threadIdx.x;
    const int bc = blockIdx.x >> 2;
    const int q = blockIdx.x & 3;
    const int c = bc & 63;
    const float a = gn_a[bc], bb = gn_b[bc];
    const size_t base0 = (size_t)bc * HW + ((size_t)q << 14);
    float bs = 0.f, bq = 0.f;
    for (int i = 0; i < 16; ++i) {
        const size_t base = base0 + (i << 10) + (t << 2);
        const ushort4 d4 = *(const ushort4*)(dy + base);
        const float4 xv = *(const float4*)(x + base);
        const float y0 = fmaxf(bf2f(d4.x) * a + bb, 0.f) + xv.x;
        const float y1 = fmaxf(bf2f(d4.y) * a + bb, 0.f) + xv.y;
        const float y2 = fmaxf(bf2f(d4.z) * a + bb, 0.f) + xv.z;
        const float y3 = fmaxf(bf2f(d4.w) * a + bb, 0.f) + xv.w;
        ushort4 o;
        o.x = (unsigned short)f2bf(y0); o.y = (unsigned short)f2bf(y1);
        o.z = (unsigned short)f2bf(y2); o.w = (unsigned short)f2bf(y3);
        *(ushort4*)(dy + base) = o;
        bs += y0 + y1 + y2 + y3;
        bq += y0 * y0 + y1 * y1 + y2 * y2 + y3 * y3;
    }
    #pragma unroll
    for (int off = 32; off; off >>= 1) { bs += __shfl_xor(bs, off); bq += __shfl_xor(bq, off); }
    __shared__ float rs[4], rq[4];
    if ((t & 63) == 0) { rs[t >> 6] = bs; rq[t >> 6] = bq; }
    __syncthreads();
    if (t == 0) {
        atomicAdd(&bn_sum[c], rs[0] + rs[1] + rs[2] + rs[3]);
        atomicAdd(&bn_sq[c],  rq[0] + rq[1] + rq[2] + rq[3]);
    }
}

__global__ void k_fin_bn(const float* __restrict__ bn_sum, const float* __restrict__ bn_sq,
                         const float* __restrict__ gamma, const float* __restrict__ beta,
                         float* __restrict__ bn_a, float* __restrict__ bn_b)
{
    const int c = threadIdx.x;
    const float n = (float)(NB * (size_t)HW);
    const float mu = bn_sum[c] / n;
    const float var = bn_sq[c] / n - mu * mu;
    const float a = rsqrtf(var + 1e-5f) * gamma[c];
    bn_a[c] = a;
    bn_b[c] = beta[c] - mu * a;
}

// ---------------------------------------------------------------------------
__global__ __launch_bounds__(256) void k_out(
    const unsigned short* __restrict__ y, const float* __restrict__ bn_a,
    const float* __restrict__ bn_b, const float* __restrict__ pa,
    const float* __restrict__ ow, const float* __restrict__ ob,
    float* __restrict__ out)
{
    const int t = threadIdx.x;
    const int b = blockIdx.x >> 6;
    const int p = ((blockIdx.x & 63) << 10) + (t << 2);
    const float alpha = pa[0];
    const float obv = ob[0];
    float a0 = obv, a1 = obv, a2 = obv, a3 = obv;
    for (int c = 0; c < CB; ++c) {
        const ushort4 v = *(const ushort4*)(y + ((size_t)(b * CB + c)) * HW + p);
        const float s = bn_a[c], sh = bn_b[c], w = ow[c];
        float t0 = bf2f(v.x) * s + sh; t0 = t0 >= 0.f ? t0 : alpha * t0; a0 += w * t0;
        float t1 = bf2f(v.y) * s + sh; t1 = t1 >= 0.f ? t1 : alpha * t1; a1 += w * t1;
        float t2 = bf2f(v.z) * s + sh; t2 = t2 >= 0.f ? t2 : alpha * t2; a2 += w * t2;
        float t3 = bf2f(v.w) * s + sh; t3 = t3 >= 0.f ? t3 : alpha * t3; a3 += w * t3;
    }
    float4 o = {a0, a1, a2, a3};
    *(float4*)(out + (size_t)b * HW + p) = o;
}

// ---------------------------------------------------------------------------
extern "C" void kernel_launch(void* const* d_in, const int* in_sizes, int n_in,
                              void* d_out, int out_size, void* d_ws, size_t ws_size,
                              hipStream_t stream)
{
    const float* x        = (const float*)d_in[0];
    const float* ca_w1    = (const float*)d_in[1];
    const float* ca_w2    = (const float*)d_in[2];
    const float* sa_w     = (const float*)d_in[3];
    const float* gate_w   = (const float*)d_in[4];
    // d_in[5..8]: offset branch — dead in forward math, skipped
    const float* dsc_w    = (const float*)d_in[9];
    const float* dsc_b    = (const float*)d_in[10];
    const float* gn_gamma = (const float*)d_in[11];
    const float* gn_beta  = (const float*)d_in[12];
    const float* bn_gamma = (const float*)d_in[13];
    const float* bn_beta  = (const float*)d_in[14];
    const float* prelu_a  = (const float*)d_in[15];
    const float* out_w    = (const float*)d_in[16];
    const float* out_b    = (const float*)d_in[17];
    float* out = (float*)d_out;

    char* ws = (char*)d_ws;
    size_t off = 0;
    auto alloc = [&](size_t bytes) -> char* {
        char* p = ws + off;
        off = (off + bytes + 255) & ~(size_t)255;
        return p;
    };
    unsigned short* dbuf = (unsigned short*)alloc((size_t)NB * CB * HW * 2);
    float* s_avg = (float*)alloc((size_t)NB * HW * 4);
    float* s_max = (float*)alloc((size_t)NB * HW * 4);
    float* sa    = (float*)alloc((size_t)NB * HW * 4);
    float* cav   = (float*)alloc(512 * 4);
    float* gn_a  = (float*)alloc(512 * 4);
    float* gn_b  = (float*)alloc(512 * 4);
    float* bn_a  = (float*)alloc(64 * 4);
    float* bn_b  = (float*)alloc(64 * 4);
    char* stats  = alloc(1408 * 4);
    float*    pool_sum = (float*)stats;
    unsigned* pool_max = (unsigned*)(stats + 512 * 4);
    float*    gn_sum   = (float*)(stats + 1024 * 4);
    float*    gn_sq    = (float*)(stats + 1152 * 4);
    float*    bn_sum   = (float*)(stats + 1280 * 4);
    float*    bn_sq    = (float*)(stats + 1344 * 4);
    (void)in_sizes; (void)n_in; (void)out_size; (void)ws_size;

    hipMemsetAsync(stats, 0, 1408 * 4, stream);

    k_stats <<<NB * 64,      256, 0, stream>>>(x, pool_sum, pool_max, s_avg, s_max);
    k_ca    <<<NB,            64, 0, stream>>>(pool_sum, pool_max, ca_w1, ca_w2, cav);
    k_saconv<<<NB * 256,     256, 0, stream>>>(s_avg, s_max, sa_w, sa);
    k_main  <<<NB * 512,     256, 0, stream>>>(x, sa, cav, gate_w, dsc_w, dsc_b, dbuf, gn_sum, gn_sq);
    k_fin_gn<<<1,            512, 0, stream>>>(gn_sum, gn_sq, gn_gamma, gn_beta, gn_a, gn_b);
    k_gnbn  <<<NB * CB * 4,  256, 0, stream>>>(x, dbuf, gn_a, gn_b, bn_sum, bn_sq);
    k_fin_bn<<<1,             64, 0, stream>>>(bn_sum, bn_sq, bn_gamma, bn_beta, bn_a, bn_b);
    k_out   <<<NB * 64,      256, 0, stream>>>(dbuf, bn_a, bn_b, prelu_a, out_w, out_b, out);
}